// Round 14
// baseline (83.532 us; speedup 1.0000x reference)
//
#include <hip/hip_runtime.h>
#include <hip/hip_bf16.h>

#define B_GR   16
#define N_PER  1024
#define M_PER  4096
#define NVEC   64
#define FDIM   192      // 3*NVEC
#define FSKIP  64
#define HID    256
#define ODIM   128
#define N_TOT  (B_GR * N_PER)   // 16384
#define M_TOT  (B_GR * M_PER)   // 65536

typedef __attribute__((ext_vector_type(8))) short short8v;   // 8 bf16 = 4 VGPR
typedef __attribute__((ext_vector_type(4))) float f32x4;     // MFMA acc

__device__ __forceinline__ unsigned short f2bf(float f) {
    __hip_bfloat16 h = __float2bfloat16(f);   // RNE
    return *reinterpret_cast<unsigned short*>(&h);
}

// swizzled element index into a [64][256] bf16 row-major LDS tile.
__device__ __forceinline__ int hsw(int r, int e) {
    return r * 256 + (e ^ ((r & 7) << 3));
}

// ---------------------------------------------------------------------------
// Kernel 0: prep — W1/W2 f32 -> bf16 [c][k] transposed; pos -> pos4
// (x,y,z,|p|^2) padded table so the KNN scan can read GLOBAL (L1-resident)
// instead of hammering the LDS pipe.
// ---------------------------------------------------------------------------
__global__ __launch_bounds__(256) void wprep_kernel(
    const float* __restrict__ W1, const float* __restrict__ W2,
    const float* __restrict__ pos,
    unsigned short* __restrict__ wt1, unsigned short* __restrict__ wt2,
    float4* __restrict__ pos4)
{
    const int i = blockIdx.x * 256 + threadIdx.x;
    if (i < 65536) {                         // W1: 256x256
        const int k = i >> 8, c = i & 255;
        wt1[c * 256 + k] = f2bf(W1[i]);
    } else if (i < 98304) {                  // W2: 256x128
        const int j = i - 65536;
        const int k = j >> 7, c = j & 127;
        wt2[c * 256 + k] = f2bf(W2[j]);
    } else {                                 // pos4: 16384 points
        const int p = i - 98304;
        const float* pp = pos + (size_t)p * 3;
        float a0 = pp[0], a1 = pp[1], a2 = pp[2];
        pos4[p] = make_float4(a0, a1, a2, a0*a0 + a1*a1 + a2*a2);
    }
}

// ---------------------------------------------------------------------------
// Kernel 1: fully fused KNN + edge-transform + MFMA MLP.
// r14 = r13 core + ONE theme: scan reads candidates from GLOBAL pos4
//   (L1-resident 16 KB/batch thanks to XCD swizzle) instead of an LDS cache.
//   r13's null (dual-acc ILP no-op) proved the scan was LDS-PIPE-bound
//   (~20 us of ds_read_b128 serialization per CU), not VALU-latency-bound.
//   Cascade: pc cache + fill + first barrier deleted; x_skip staged at top;
//   scan->U->phaseA is wave-self-contained (q=tid>>3 spans exactly this
//   wave's 8 rows; within-wave LDS RAW ordered by lgkmcnt) -> barriers 5->3,
//   waves fully desync until GEMM1.
// REGISTER BUDGET RULE (r10): accs = 32 AGPR unified; keep scalar VGPR low.
// HISTORY: r6 (512,8) spill 394us; r7 (512,5) spill 194us; r8 fat scan
// 157us; r10 bundle 101us; r13 dual-acc neutral. Keep 8-sublane scan,
// (512,2), 4x2 GEMM grid, XCD swizzle (FETCH 52->17MB), fused phase U.
// ---------------------------------------------------------------------------
__global__ __launch_bounds__(512, 2) void fused_kernel(
    const float* __restrict__ x,             // [N_TOT,192]
    const float4* __restrict__ pos4,         // [N_TOT] (x,y,z,|p|^2)
    const float* __restrict__ pos_skip,      // [M_TOT,3]
    const float* __restrict__ x_skip,        // [M_TOT,64]
    const float* __restrict__ lframes,       // [N_TOT,3,3]
    const float* __restrict__ lframes_skip,  // [M_TOT,3,3]
    const unsigned short* __restrict__ wt1,  // [256][256] bf16 (c-major)
    const float* __restrict__ b1,            // [256]
    const unsigned short* __restrict__ wt2,  // [128][256] bf16 (c-major)
    const float* __restrict__ b2,            // [128]
    float* __restrict__ out)                 // [M_TOT,128]
{
    __shared__ __align__(16) unsigned short hb[64 * 256];   // 32 KB h tile
    __shared__ __align__(16) float Usc[64 * 28];            // 7 KB scaled-U
    __shared__ int idxL[64 * 3];                            // local nbr idx

    const int tid  = threadIdx.x;
    const int lane = tid & 63;
    const int wv   = tid >> 6;               // 0..7
    const int raw  = blockIdx.x;
    const int blk  = (raw & 7) * 128 + (raw >> 3);   // XCD-contiguous batches
    const int lo   = lane & 15;
    const int hi   = lane >> 4;
    const int b    = blk >> 6;               // 64 blocks per batch

    const float4* __restrict__ gp4 = pos4 + (size_t)b * N_PER;

    // ---- x_skip staging for this wave's 8 rows (no LDS aliasing, no bar) ---
    #pragma unroll
    for (int rr = 0; rr < 8; ++rr) {
        const int r = wv * 8 + rr;
        const int m = blk * 64 + r;
        hb[hsw(r, 192+lane)] = f2bf(x_skip[(size_t)m*FSKIP + lane]);
    }

    // ---------------- Phase K: global-pos4 top-3 scan ----------------------
    {
        const int q   = tid >> 3;            // query row 0..63 (own wave's 8)
        const int sub = tid & 7;
        const int m   = blk * 64 + q;
        float nqx, nqy, nqz, qq;
        {
            const float qx = pos_skip[m*3+0], qy = pos_skip[m*3+1],
                        qz = pos_skip[m*3+2];
            qq  = qx*qx + qy*qy + qz*qz;
            nqx = -2.0f*qx; nqy = -2.0f*qy; nqz = -2.0f*qz;
        }

        // two independent accumulator sets (hide ~200cy L1/VMEM latency)
        float d0 = 1e30f, d1 = 1e30f, d2 = 1e30f;
        int   i0 = 0,     i1 = 0,     i2 = 0;
        float e0 = 1e30f, e1 = 1e30f, e2 = 1e30f;
        int   k0 = 0,     k1 = 0,     k2 = 0;
        #pragma unroll 4
        for (int t = 0; t < 64; ++t) {
            const int ja = t*16 + sub;       // even 8-group
            const int jb = ja + 8;           // odd 8-group
            float4 ca = gp4[ja];
            float4 cb = gp4[jb];
            float ra = fmaf(nqx, ca.x, fmaf(nqy, ca.y, fmaf(nqz, ca.z, qq + ca.w)));
            float rb = fmaf(nqx, cb.x, fmaf(nqy, cb.y, fmaf(nqz, cb.z, qq + cb.w)));
            {
                bool c0 = ra < d0, c1 = ra < d1, c2 = ra < d2;
                i2 = c2 ? (c1 ? i1 : ja) : i2;
                i1 = c1 ? (c0 ? i0 : ja) : i1;
                i0 = c0 ? ja : i0;
                d2 = c2 ? (c1 ? d1 : ra) : d2;
                d1 = c1 ? (c0 ? d0 : ra) : d1;
                d0 = c0 ? ra : d0;
            }
            {
                bool c0 = rb < e0, c1 = rb < e1, c2 = rb < e2;
                k2 = c2 ? (c1 ? k1 : jb) : k2;
                k1 = c1 ? (c0 ? k0 : jb) : k1;
                k0 = c0 ? jb : k0;
                e2 = c2 ? (c1 ? e1 : rb) : e2;
                e1 = c1 ? (c0 ? e0 : rb) : e1;
                e0 = c0 ? rb : e0;
            }
        }
        // merge B into A, lexicographic (d, j) — exact top_k tie rule
        {
            const float ee[3] = {e0, e1, e2};
            const int   jj[3] = {k0, k1, k2};
            #pragma unroll
            for (int s = 0; s < 3; ++s) {
                const float e = ee[s]; const int j = jj[s];
                bool c0 = (e < d0) || (e == d0 && j < i0);
                bool c1 = (e < d1) || (e == d1 && j < i1);
                bool c2 = (e < d2) || (e == d2 && j < i2);
                i2 = c2 ? (c1 ? i1 : j) : i2;
                i1 = c1 ? (c0 ? i0 : j) : i1;
                i0 = c0 ? j : i0;
                d2 = c2 ? (c1 ? d1 : e) : d2;
                d1 = c1 ? (c0 ? d0 : e) : d1;
                d0 = c0 ? e : d0;
            }
        }
        // 3-level butterfly merge across the 8 sublanes, lexicographic (d, j)
        #pragma unroll
        for (int mask = 1; mask <= 4; mask <<= 1) {
            float f0 = __shfl_xor(d0, mask), f1 = __shfl_xor(d1, mask),
                  f2 = __shfl_xor(d2, mask);
            int   j0 = __shfl_xor(i0, mask), j1 = __shfl_xor(i1, mask),
                  j2 = __shfl_xor(i2, mask);
            const float ee[3] = {f0, f1, f2};
            const int   jj[3] = {j0, j1, j2};
            #pragma unroll
            for (int s = 0; s < 3; ++s) {
                const float e = ee[s]; const int j = jj[s];
                bool c0 = (e < d0) || (e == d0 && j < i0);
                bool c1 = (e < d1) || (e == d1 && j < i1);
                bool c2 = (e < d2) || (e == d2 && j < i2);
                i2 = c2 ? (c1 ? i1 : j) : i2;
                i1 = c1 ? (c0 ? i0 : j) : i1;
                i0 = c0 ? j : i0;
                d2 = c2 ? (c1 ? d1 : e) : d2;
                d1 = c1 ? (c0 ? d0 : e) : d1;
                d0 = c0 ? e : d0;
            }
        }

        // -------- fused phase U (producer lanes are in THIS wave) ----------
        if (sub < 3) {
            const int jl = (sub == 0) ? i0 : (sub == 1) ? i1 : i2;
            idxL[q*3 + sub] = jl;            // local index, for phase A

            const float qx = -0.5f*nqx, qy = -0.5f*nqy, qz = -0.5f*nqz;
            float w[3];
            const int jls[3] = {i0, i1, i2};
            #pragma unroll
            for (int s = 0; s < 3; ++s) {
                float4 c = gp4[jls[s]];
                float dx = c.x - qx, dy = c.y - qy, dz = c.z - qz;
                w[s] = 1.0f / fmaxf(dx*dx + dy*dy + dz*dz, 1e-16f);
            }
            const float wsub = (sub == 0) ? w[0] : (sub == 1) ? w[1] : w[2];
            const float sS   = wsub / (w[0] + w[1] + w[2]);
            const int   nb   = b * N_PER + jl;

            float RyS[9], Rx[9];
            #pragma unroll
            for (int t = 0; t < 9; ++t) RyS[t] = sS * lframes_skip[(size_t)m*9 + t];
            #pragma unroll
            for (int t = 0; t < 9; ++t) Rx[t] = lframes[(size_t)nb*9 + t];

            float* dst = &Usc[q*28 + sub*9];
            #pragma unroll
            for (int a = 0; a < 3; ++a)
                #pragma unroll
                for (int c = 0; c < 3; ++c)
                    dst[a*3+c] = RyS[a*3+0]*Rx[c*3+0]
                               + RyS[a*3+1]*Rx[c*3+1]
                               + RyS[a*3+2]*Rx[c*3+2];
        }
    }
    // NO barrier: phase A below uses only this wave's rows' idxL/Usc
    // (written by this wave; within-wave LDS RAW ordered by lgkmcnt).

    // ---------------- Phase A: y columns of h (bf16) ----------------
    for (int rr = 0; rr < 8; ++rr) {
        const int r = wv * 8 + rr;
        const int nbs[3] = {b*N_PER + idxL[r*3+0],
                            b*N_PER + idxL[r*3+1],
                            b*N_PER + idxL[r*3+2]};

        float Ub[28];
        float4* Ub4 = reinterpret_cast<float4*>(Ub);
        #pragma unroll
        for (int t = 0; t < 7; ++t)
            Ub4[t] = *reinterpret_cast<const float4*>(&Usc[r*28 + t*4]);  // bcast

        float n0 = 0.f, n1 = 0.f, n2 = 0.f;
        #pragma unroll
        for (int k = 0; k < 3; ++k) {
            const float* xp = x + (size_t)nbs[k]*FDIM + lane*3;
            const float v0 = xp[0], v1 = xp[1], v2 = xp[2];
            const int o = k*9;
            n0 += Ub[o+0]*v0 + Ub[o+1]*v1 + Ub[o+2]*v2;
            n1 += Ub[o+3]*v0 + Ub[o+4]*v1 + Ub[o+5]*v2;
            n2 += Ub[o+6]*v0 + Ub[o+7]*v1 + Ub[o+8]*v2;
        }
        hb[hsw(r, lane*3+0)] = f2bf(n0);
        hb[hsw(r, lane*3+1)] = f2bf(n1);
        hb[hsw(r, lane*3+2)] = f2bf(n2);
    }
    __syncthreads();   // h complete; GEMM reads all rows

    // ---------------- GEMM1: hidden = relu(h @ W1 + b1) ----------------
    // wave wv covers cols [wv*32, wv*32+32)
    f32x4 acc[4][2];
    #pragma unroll
    for (int fi = 0; fi < 4; ++fi)
        #pragma unroll
        for (int ci = 0; ci < 2; ++ci) acc[fi][ci] = (f32x4)0.f;

    for (int ks = 0; ks < 8; ++ks) {
        const int kk = ks*32 + hi*8;
        short8v a[4], bf[2];
        #pragma unroll
        for (int fi = 0; fi < 4; ++fi) {
            const int r = fi*16 + lo;
            a[fi] = *reinterpret_cast<const short8v*>(
                &hb[r*256 + (kk ^ ((lo & 7) << 3))]);
        }
        #pragma unroll
        for (int ci = 0; ci < 2; ++ci) {
            const int cb = wv*32 + ci*16 + lo;
            bf[ci] = *reinterpret_cast<const short8v*>(&wt1[cb*256 + kk]);
        }
        #pragma unroll
        for (int fi = 0; fi < 4; ++fi)
            #pragma unroll
            for (int ci = 0; ci < 2; ++ci)
                acc[fi][ci] = __builtin_amdgcn_mfma_f32_16x16x32_bf16(
                    a[fi], bf[ci], acc[fi][ci], 0, 0, 0);
    }
    __syncthreads();   // all GEMM1 reads of h complete

    {
        float b1v[2];
        #pragma unroll
        for (int ci = 0; ci < 2; ++ci) b1v[ci] = b1[wv*32 + ci*16 + lo];
        #pragma unroll
        for (int fi = 0; fi < 4; ++fi)
            #pragma unroll
            for (int ci = 0; ci < 2; ++ci)
                #pragma unroll
                for (int q = 0; q < 4; ++q) {
                    const int r = fi*16 + hi*4 + q;
                    const int c = wv*32 + ci*16 + lo;
                    hb[hsw(r, c)] = f2bf(fmaxf(acc[fi][ci][q] + b1v[ci], 0.f));
                }
    }
    __syncthreads();

    // ---------------- GEMM2: out = hidden @ W2 + b2 ----------------
    // wave wv covers cols [wv*16, wv*16+16)
    f32x4 acc2[4];
    #pragma unroll
    for (int fi = 0; fi < 4; ++fi) acc2[fi] = (f32x4)0.f;

    for (int ks = 0; ks < 8; ++ks) {
        const int kk = ks*32 + hi*8;
        short8v a[4], bf;
        #pragma unroll
        for (int fi = 0; fi < 4; ++fi) {
            const int r = fi*16 + lo;
            a[fi] = *reinterpret_cast<const short8v*>(
                &hb[r*256 + (kk ^ ((lo & 7) << 3))]);
        }
        {
            const int cb = wv*16 + lo;
            bf = *reinterpret_cast<const short8v*>(&wt2[cb*256 + kk]);
        }
        #pragma unroll
        for (int fi = 0; fi < 4; ++fi)
            acc2[fi] = __builtin_amdgcn_mfma_f32_16x16x32_bf16(
                a[fi], bf, acc2[fi], 0, 0, 0);
    }

    {
        const float b2v = b2[wv*16 + lo];
        #pragma unroll
        for (int fi = 0; fi < 4; ++fi)
            #pragma unroll
            for (int q = 0; q < 4; ++q) {
                const int r = fi*16 + hi*4 + q;
                const int c = wv*16 + lo;
                out[(size_t)(blk*64 + r)*ODIM + c] = acc2[fi][q] + b2v;
            }
    }
}

// ---------------------------------------------------------------------------
// Kernel 2: pass-through tail: pos_skip, batch_skip (int32), lframes_skip
// ---------------------------------------------------------------------------
__global__ __launch_bounds__(256) void tail_kernel(
    const float* __restrict__ pos_skip,
    const int*   __restrict__ batch_skip,
    const float* __restrict__ lframes_skip,
    float* __restrict__ dst)
{
    const int i = blockIdx.x * 256 + threadIdx.x;
    const int P = M_TOT * 3;
    const int Q = P + M_TOT;
    const int R = Q + M_TOT * 9;
    if (i < P)      dst[i] = pos_skip[i];
    else if (i < Q) dst[i] = (float)batch_skip[i - P];
    else if (i < R) dst[i] = lframes_skip[i - Q];
}

extern "C" void kernel_launch(void* const* d_in, const int* in_sizes, int n_in,
                              void* d_out, int out_size, void* d_ws, size_t ws_size,
                              hipStream_t stream) {
    const float* x            = (const float*)d_in[0];
    const float* pos          = (const float*)d_in[1];
    const float* pos_skip     = (const float*)d_in[2];
    const float* x_skip       = (const float*)d_in[3];
    const float* lframes      = (const float*)d_in[4];
    const float* lframes_skip = (const float*)d_in[5];
    const float* W1           = (const float*)d_in[6];
    const float* b1           = (const float*)d_in[7];
    const float* W2           = (const float*)d_in[8];
    const float* b2           = (const float*)d_in[9];
    const int*   batch_skip   = (const int*)d_in[11];

    char* ws = (char*)d_ws;
    unsigned short* wt1  = (unsigned short*)ws;                  // 131072 B
    unsigned short* wt2  = (unsigned short*)(ws + 131072);       // 65536 B
    float4*         pos4 = (float4*)(ws + 131072 + 65536);       // 262144 B
    float* out = (float*)d_out;

    // 65536 (wt1) + 32768 (wt2) + 16384 (pos4) threads = 448 blocks
    wprep_kernel<<<448, 256, 0, stream>>>(W1, W2, pos, wt1, wt2, pos4);

    fused_kernel<<<M_TOT/64, 512, 0, stream>>>(x, pos4, pos_skip, x_skip,
                                               lframes, lframes_skip,
                                               wt1, b1, wt2, b2, out);

    float* tail = out + (size_t)M_TOT * ODIM;
    const int tail_elems = M_TOT * (3 + 1 + 9);
    tail_kernel<<<(tail_elems + 255)/256, 256, 0, stream>>>(
        pos_skip, batch_skip, lframes_skip, tail);
}

// Round 16
// 66.255 us; speedup vs baseline: 1.2608x; 1.2608x over previous
//
#include <hip/hip_runtime.h>
#include <hip/hip_bf16.h>

#define B_GR   16
#define N_PER  1024
#define M_PER  4096
#define NVEC   64
#define FDIM   192      // 3*NVEC
#define FSKIP  64
#define HID    256
#define ODIM   128
#define N_TOT  (B_GR * N_PER)   // 16384
#define M_TOT  (B_GR * M_PER)   // 65536

typedef __attribute__((ext_vector_type(8))) short short8v;   // 8 bf16 = 4 VGPR
typedef __attribute__((ext_vector_type(4))) float f32x4;     // MFMA acc

__device__ __forceinline__ unsigned short f2bf(float f) {
    __hip_bfloat16 h = __float2bfloat16(f);   // RNE
    return *reinterpret_cast<unsigned short*>(&h);
}

// swizzled element index into a [64][256] bf16 row-major LDS tile.
__device__ __forceinline__ int hsw(int r, int e) {
    return r * 256 + (e ^ ((r & 7) << 3));
}

// ---------------------------------------------------------------------------
// Kernel 0: merged prep + tail.
//   i in [0, 65536):        W1 f32 -> bf16 [c][k] transposed
//   i in [65536, 98304):    W2 f32 -> bf16 [c][k] transposed
//   i in [98304, 950272):   tuple tail: pos_skip | batch_skip (int32->f32)
//                           | lframes_skip  (written to out + M*128)
// Merging kills one kernel launch (~2-4 us on the serialized stream).
// ---------------------------------------------------------------------------
__global__ __launch_bounds__(256) void prep_tail_kernel(
    const float* __restrict__ W1, const float* __restrict__ W2,
    const float* __restrict__ pos_skip,
    const int*   __restrict__ batch_skip,
    const float* __restrict__ lframes_skip,
    unsigned short* __restrict__ wt1, unsigned short* __restrict__ wt2,
    float* __restrict__ dst)
{
    const int i = blockIdx.x * 256 + threadIdx.x;
    if (i < 65536) {                          // W1: 256x256
        const int k = i >> 8, c = i & 255;
        wt1[c * 256 + k] = f2bf(W1[i]);
    } else if (i < 98304) {                   // W2: 256x128
        const int j = i - 65536;
        const int k = j >> 7, c = j & 127;
        wt2[c * 256 + k] = f2bf(W2[j]);
    } else {                                  // tail: 851968 elements
        const int t = i - 98304;
        const int P = M_TOT * 3;
        const int Q = P + M_TOT;
        if (t < P)      dst[t] = pos_skip[t];
        else if (t < Q) dst[t] = (float)batch_skip[t - P];
        else            dst[t] = lframes_skip[t - Q];
    }
}

// ---------------------------------------------------------------------------
// Kernel 1: fully fused KNN + edge-transform + MFMA MLP.
// == r12 CHAMPION VERBATIM (68.6 us, VGPR 36) ==
//  - 8-sublane-per-query scan, fmaf ranking form, strict-< local insert,
//    3-level shfl_xor lexicographic butterfly (exact lax.top_k tie rule)
//  - phase U fused into scan tail (all sublanes hold merged top-3)
//  - early x_skip staging rows 32-63 (hb rows>=32 never alias pc)
//  - XCD swizzle blk=(raw&7)*128+raw/8 (FETCH 52->17 MB, r11 isolated)
//  - GEMM1 4x2 frags/wave (wv covers 32 cols), GEMM2 (16 cols)
// EVIDENCE LOG (do not regress):
//  r6 (512,8) VGPR-cap 32 -> HBM spill, 394us | r7 (512,5) cap 48, 194us
//  r8 4-query fat scan at natural regs: 157us | r10 bundle VGPR52: 101us
//  r13 dual-acc same-query ILP: neutral (scan is LDS-pipe-bound, not
//    VALU-latency-bound) | r14 global-pos4 scan: 83.5us (L1 pipe < LDS pipe;
//    VGPR 48) | r15 2-query/thread scan: CORRECTNESS FAIL (absmax 0.598,
//    defect not identified in 5 passes — theme retired).
// REGISTER RULE (r10): accs = 32 AGPR unified with VGPR; cliffs at 64/128.
// ---------------------------------------------------------------------------
__global__ __launch_bounds__(512, 2) void fused_kernel(
    const float* __restrict__ x,             // [N_TOT,192]
    const float* __restrict__ pos,           // [N_TOT,3]
    const float* __restrict__ pos_skip,      // [M_TOT,3]
    const float* __restrict__ x_skip,        // [M_TOT,64]
    const float* __restrict__ lframes,       // [N_TOT,3,3]
    const float* __restrict__ lframes_skip,  // [M_TOT,3,3]
    const unsigned short* __restrict__ wt1,  // [256][256] bf16 (c-major)
    const float* __restrict__ b1,            // [256]
    const unsigned short* __restrict__ wt2,  // [128][256] bf16 (c-major)
    const float* __restrict__ b2,            // [128]
    float* __restrict__ out)                 // [M_TOT,128]
{
    __shared__ __align__(16) char smraw[64 * 256 * 2];   // 32 KB: pc ∪ hb
    __shared__ __align__(16) float Usc[64 * 28];         // 7 KB scaled-U
    __shared__ int idxL[64 * 3];                         // LOCAL nbr indices

    float4*         pc = reinterpret_cast<float4*>(smraw);          // [1024]
    unsigned short* hb = reinterpret_cast<unsigned short*>(smraw);  // [64*256]

    const int tid  = threadIdx.x;
    const int lane = tid & 63;
    const int wv   = tid >> 6;               // 0..7
    const int raw  = blockIdx.x;
    const int blk  = (raw & 7) * 128 + (raw >> 3);   // XCD-contiguous batches
    const int lo   = lane & 15;
    const int hi   = lane >> 4;
    const int b    = blk >> 6;               // 64 blocks per batch

    // ---------------- Phase K: candidate cache + top-3 scan ----------------
    #pragma unroll
    for (int k = 0; k < 2; ++k) {
        const int j = tid + k * 512;
        const float* p = pos + (size_t)(b * N_PER + j) * 3;
        float a0 = p[0], a1 = p[1], a2 = p[2];
        pc[j] = make_float4(a0, a1, a2, a0*a0 + a1*a1 + a2*a2);
    }
    __syncthreads();

    {
        const int q   = tid >> 3;            // query row 0..63
        const int sub = tid & 7;
        const int m   = blk * 64 + q;
        float nqx, nqy, nqz, qq;
        {
            const float qx = pos_skip[m*3+0], qy = pos_skip[m*3+1],
                        qz = pos_skip[m*3+2];
            qq  = qx*qx + qy*qy + qz*qz;
            nqx = -2.0f*qx; nqy = -2.0f*qy; nqz = -2.0f*qz;
        }

        float d0 = 1e30f, d1 = 1e30f, d2 = 1e30f;
        int   i0 = 0,     i1 = 0,     i2 = 0;
        #pragma unroll 4
        for (int t = 0; t < 128; ++t) {
            const int j = t*8 + sub;         // wave reads 128B bcast x8
            float4 c = pc[j];
            float r = fmaf(nqx, c.x, fmaf(nqy, c.y, fmaf(nqz, c.z, qq + c.w)));
            bool c0 = r < d0, c1 = r < d1, c2 = r < d2;
            i2 = c2 ? (c1 ? i1 : j) : i2;
            i1 = c1 ? (c0 ? i0 : j) : i1;
            i0 = c0 ? j : i0;
            d2 = c2 ? (c1 ? d1 : r) : d2;
            d1 = c1 ? (c0 ? d0 : r) : d1;
            d0 = c0 ? r : d0;
        }
        // 3-level butterfly merge across the 8 sublanes, lexicographic (d, j)
        #pragma unroll
        for (int mask = 1; mask <= 4; mask <<= 1) {
            float e0 = __shfl_xor(d0, mask), e1 = __shfl_xor(d1, mask),
                  e2 = __shfl_xor(d2, mask);
            int   j0 = __shfl_xor(i0, mask), j1 = __shfl_xor(i1, mask),
                  j2 = __shfl_xor(i2, mask);
            const float ee[3] = {e0, e1, e2};
            const int   jj[3] = {j0, j1, j2};
            #pragma unroll
            for (int s = 0; s < 3; ++s) {
                const float e = ee[s]; const int j = jj[s];
                bool c0 = (e < d0) || (e == d0 && j < i0);
                bool c1 = (e < d1) || (e == d1 && j < i1);
                bool c2 = (e < d2) || (e == d2 && j < i2);
                i2 = c2 ? (c1 ? i1 : j) : i2;
                i1 = c1 ? (c0 ? i0 : j) : i1;
                i0 = c0 ? j : i0;
                d2 = c2 ? (c1 ? d1 : e) : d2;
                d1 = c1 ? (c0 ? d0 : e) : d1;
                d0 = c0 ? e : d0;
            }
        }

        // -------- fused phase U: all 8 sublanes hold the merged top-3 -------
        if (sub < 3) {
            const int jl = (sub == 0) ? i0 : (sub == 1) ? i1 : i2;
            idxL[q*3 + sub] = jl;            // local index, for phase A

            const float qx = -0.5f*nqx, qy = -0.5f*nqy, qz = -0.5f*nqz;
            float w[3];
            const int jls[3] = {i0, i1, i2};
            #pragma unroll
            for (int s = 0; s < 3; ++s) {
                float4 c = pc[jls[s]];
                float dx = c.x - qx, dy = c.y - qy, dz = c.z - qz;
                w[s] = 1.0f / fmaxf(dx*dx + dy*dy + dz*dz, 1e-16f);
            }
            const float wsub = (sub == 0) ? w[0] : (sub == 1) ? w[1] : w[2];
            const float sS   = wsub / (w[0] + w[1] + w[2]);
            const int   nb   = b * N_PER + jl;

            float RyS[9], Rx[9];
            #pragma unroll
            for (int t = 0; t < 9; ++t) RyS[t] = sS * lframes_skip[(size_t)m*9 + t];
            #pragma unroll
            for (int t = 0; t < 9; ++t) Rx[t] = lframes[(size_t)nb*9 + t];

            float* dst = &Usc[q*28 + sub*9];
            #pragma unroll
            for (int a = 0; a < 3; ++a)
                #pragma unroll
                for (int c = 0; c < 3; ++c)
                    dst[a*3+c] = RyS[a*3+0]*Rx[c*3+0]
                               + RyS[a*3+1]*Rx[c*3+1]
                               + RyS[a*3+2]*Rx[c*3+2];
        }
    }

    // early x_skip staging for rows 32-63 (hb rows >=32 never alias pc)
    if (wv >= 4) {
        #pragma unroll
        for (int rr = 0; rr < 8; ++rr) {
            const int r = wv * 8 + rr;       // 32..63
            const int m = blk * 64 + r;
            hb[hsw(r, 192+lane)] = f2bf(x_skip[(size_t)m*FSKIP + lane]);
        }
    }
    __syncthreads();   // idxL + Usc visible; pc reads done before hb overwrite

    // ---------------- Phase A: build h = [y | x_skip] (bf16) ----------------
    for (int rr = 0; rr < 8; ++rr) {
        const int r = wv * 8 + rr;
        const int m = blk * 64 + r;
        const int nbs[3] = {b*N_PER + idxL[r*3+0],
                            b*N_PER + idxL[r*3+1],
                            b*N_PER + idxL[r*3+2]};

        float Ub[28];
        float4* Ub4 = reinterpret_cast<float4*>(Ub);
        #pragma unroll
        for (int t = 0; t < 7; ++t)
            Ub4[t] = *reinterpret_cast<const float4*>(&Usc[r*28 + t*4]);  // bcast

        float n0 = 0.f, n1 = 0.f, n2 = 0.f;
        #pragma unroll
        for (int k = 0; k < 3; ++k) {
            const float* xp = x + (size_t)nbs[k]*FDIM + lane*3;
            const float v0 = xp[0], v1 = xp[1], v2 = xp[2];
            const int o = k*9;
            n0 += Ub[o+0]*v0 + Ub[o+1]*v1 + Ub[o+2]*v2;
            n1 += Ub[o+3]*v0 + Ub[o+4]*v1 + Ub[o+5]*v2;
            n2 += Ub[o+6]*v0 + Ub[o+7]*v1 + Ub[o+8]*v2;
        }
        hb[hsw(r, lane*3+0)] = f2bf(n0);
        hb[hsw(r, lane*3+1)] = f2bf(n1);
        hb[hsw(r, lane*3+2)] = f2bf(n2);
        if (wv < 4)   // rows 32-63 already staged before the barrier
            hb[hsw(r, 192+lane)] = f2bf(x_skip[(size_t)m*FSKIP + lane]);
    }
    __syncthreads();

    // ---------------- GEMM1: hidden = relu(h @ W1 + b1) ----------------
    // wave wv covers cols [wv*32, wv*32+32)
    f32x4 acc[4][2];
    #pragma unroll
    for (int fi = 0; fi < 4; ++fi)
        #pragma unroll
        for (int ci = 0; ci < 2; ++ci) acc[fi][ci] = (f32x4)0.f;

    for (int ks = 0; ks < 8; ++ks) {
        const int kk = ks*32 + hi*8;
        short8v a[4], bf[2];
        #pragma unroll
        for (int fi = 0; fi < 4; ++fi) {
            const int r = fi*16 + lo;
            a[fi] = *reinterpret_cast<const short8v*>(
                &hb[r*256 + (kk ^ ((lo & 7) << 3))]);
        }
        #pragma unroll
        for (int ci = 0; ci < 2; ++ci) {
            const int cb = wv*32 + ci*16 + lo;
            bf[ci] = *reinterpret_cast<const short8v*>(&wt1[cb*256 + kk]);
        }
        #pragma unroll
        for (int fi = 0; fi < 4; ++fi)
            #pragma unroll
            for (int ci = 0; ci < 2; ++ci)
                acc[fi][ci] = __builtin_amdgcn_mfma_f32_16x16x32_bf16(
                    a[fi], bf[ci], acc[fi][ci], 0, 0, 0);
    }
    __syncthreads();   // all GEMM1 reads of h complete

    {
        float b1v[2];
        #pragma unroll
        for (int ci = 0; ci < 2; ++ci) b1v[ci] = b1[wv*32 + ci*16 + lo];
        #pragma unroll
        for (int fi = 0; fi < 4; ++fi)
            #pragma unroll
            for (int ci = 0; ci < 2; ++ci)
                #pragma unroll
                for (int q = 0; q < 4; ++q) {
                    const int r = fi*16 + hi*4 + q;
                    const int c = wv*32 + ci*16 + lo;
                    hb[hsw(r, c)] = f2bf(fmaxf(acc[fi][ci][q] + b1v[ci], 0.f));
                }
    }
    __syncthreads();

    // ---------------- GEMM2: out = hidden @ W2 + b2 ----------------
    // wave wv covers cols [wv*16, wv*16+16)
    f32x4 acc2[4];
    #pragma unroll
    for (int fi = 0; fi < 4; ++fi) acc2[fi] = (f32x4)0.f;

    for (int ks = 0; ks < 8; ++ks) {
        const int kk = ks*32 + hi*8;
        short8v a[4], bf;
        #pragma unroll
        for (int fi = 0; fi < 4; ++fi) {
            const int r = fi*16 + lo;
            a[fi] = *reinterpret_cast<const short8v*>(
                &hb[r*256 + (kk ^ ((lo & 7) << 3))]);
        }
        {
            const int cb = wv*16 + lo;
            bf = *reinterpret_cast<const short8v*>(&wt2[cb*256 + kk]);
        }
        #pragma unroll
        for (int fi = 0; fi < 4; ++fi)
            acc2[fi] = __builtin_amdgcn_mfma_f32_16x16x32_bf16(
                a[fi], bf, acc2[fi], 0, 0, 0);
    }

    {
        const float b2v = b2[wv*16 + lo];
        #pragma unroll
        for (int fi = 0; fi < 4; ++fi)
            #pragma unroll
            for (int q = 0; q < 4; ++q) {
                const int r = fi*16 + hi*4 + q;
                const int c = wv*16 + lo;
                out[(size_t)(blk*64 + r)*ODIM + c] = acc2[fi][q] + b2v;
            }
    }
}

extern "C" void kernel_launch(void* const* d_in, const int* in_sizes, int n_in,
                              void* d_out, int out_size, void* d_ws, size_t ws_size,
                              hipStream_t stream) {
    const float* x            = (const float*)d_in[0];
    const float* pos          = (const float*)d_in[1];
    const float* pos_skip     = (const float*)d_in[2];
    const float* x_skip       = (const float*)d_in[3];
    const float* lframes      = (const float*)d_in[4];
    const float* lframes_skip = (const float*)d_in[5];
    const float* W1           = (const float*)d_in[6];
    const float* b1           = (const float*)d_in[7];
    const float* W2           = (const float*)d_in[8];
    const float* b2           = (const float*)d_in[9];
    const int*   batch_skip   = (const int*)d_in[11];

    char* ws = (char*)d_ws;
    unsigned short* wt1 = (unsigned short*)ws;                 // 131072 B
    unsigned short* wt2 = (unsigned short*)(ws + 131072);      // 65536 B
    float* out  = (float*)d_out;
    float* tail = out + (size_t)M_TOT * ODIM;

    // merged prep + tail: 65536 + 32768 + 851968 = 950272 threads = 3712 blocks
    prep_tail_kernel<<<3712, 256, 0, stream>>>(W1, W2, pos_skip, batch_skip,
                                               lframes_skip, wt1, wt2, tail);

    fused_kernel<<<M_TOT/64, 512, 0, stream>>>(x, pos, pos_skip, x_skip,
                                               lframes, lframes_skip,
                                               wt1, b1, wt2, b2, out);
}

// Round 17
// 66.097 us; speedup vs baseline: 1.2638x; 1.0024x over previous
//
#include <hip/hip_runtime.h>
#include <hip/hip_bf16.h>

#define B_GR   16
#define N_PER  1024
#define M_PER  4096
#define NVEC   64
#define FDIM   192      // 3*NVEC
#define FSKIP  64
#define HID    256
#define ODIM   128
#define N_TOT  (B_GR * N_PER)   // 16384
#define M_TOT  (B_GR * M_PER)   // 65536

typedef __attribute__((ext_vector_type(8))) short short8v;   // 8 bf16 = 4 VGPR
typedef __attribute__((ext_vector_type(4))) float f32x4;     // MFMA acc

__device__ __forceinline__ unsigned short f2bf(float f) {
    __hip_bfloat16 h = __float2bfloat16(f);   // RNE
    return *reinterpret_cast<unsigned short*>(&h);
}

// swizzled element index into a [64][256] bf16 row-major LDS tile.
__device__ __forceinline__ int hsw(int r, int e) {
    return r * 256 + (e ^ ((r & 7) << 3));
}

// ---------------------------------------------------------------------------
// Kernel 0: merged prep + tail (r16 proven).
// ---------------------------------------------------------------------------
__global__ __launch_bounds__(256) void prep_tail_kernel(
    const float* __restrict__ W1, const float* __restrict__ W2,
    const float* __restrict__ pos_skip,
    const int*   __restrict__ batch_skip,
    const float* __restrict__ lframes_skip,
    unsigned short* __restrict__ wt1, unsigned short* __restrict__ wt2,
    float* __restrict__ dst)
{
    const int i = blockIdx.x * 256 + threadIdx.x;
    if (i < 65536) {                          // W1: 256x256
        const int k = i >> 8, c = i & 255;
        wt1[c * 256 + k] = f2bf(W1[i]);
    } else if (i < 98304) {                   // W2: 256x128
        const int j = i - 65536;
        const int k = j >> 7, c = j & 127;
        wt2[c * 256 + k] = f2bf(W2[j]);
    } else {                                  // tail: 851968 elements
        const int t = i - 98304;
        const int P = M_TOT * 3;
        const int Q = P + M_TOT;
        if (t < P)      dst[t] = pos_skip[t];
        else if (t < Q) dst[t] = (float)batch_skip[t - P];
        else            dst[t] = lframes_skip[t - Q];
    }
}

// ---------------------------------------------------------------------------
// Kernel 1: fully fused KNN + edge-transform + MFMA MLP.
// r17 = r16 champion + REGISTER DIET (goal: total VGPR+AGPR <= 64/wave so
// waves/SIMD go 4 -> 8; occupancy 48% -> ~75%; kernel is phase-serialization
// bound at 2 blocks/CU, no pipe saturated):
//  (1) scan unroll 4->2 (in-flight candidate regs 16->8; scan is LDS-pipe-
//      bound per r13 evidence, not latency-bound, so no throughput loss)
//  (2) phase-U computes U row-interleaved: load one Rx row per c iteration
//      (live 9+3 floats vs 9+9)
//  (3) Usc padded to [64][3][12] (16B-aligned per-k chunks); phase A loads
//      12 floats per neighbor instead of all 28 (peak live 12 vs 28)
// LDS = 32768 + 9216 + 768 = 42752 B -> 3 blocks/CU by LDS.
// EVIDENCE LOG: r6 (512,8) spill 394us | r7 (512,5) spill 194us | r8 fat
// scan 157us | r10 bundle VGPR52 101us | r13 dual-acc null (scan LDS-pipe-
// bound) | r14 global-scan 83.5us (L1 < LDS pipe) | r15 2-query scan broken.
// REGISTER RULE (r10): cliffs at 64/128 total (VGPR+32 AGPR unified).
// ---------------------------------------------------------------------------
__global__ __launch_bounds__(512, 2) void fused_kernel(
    const float* __restrict__ x,             // [N_TOT,192]
    const float* __restrict__ pos,           // [N_TOT,3]
    const float* __restrict__ pos_skip,      // [M_TOT,3]
    const float* __restrict__ x_skip,        // [M_TOT,64]
    const float* __restrict__ lframes,       // [N_TOT,3,3]
    const float* __restrict__ lframes_skip,  // [M_TOT,3,3]
    const unsigned short* __restrict__ wt1,  // [256][256] bf16 (c-major)
    const float* __restrict__ b1,            // [256]
    const unsigned short* __restrict__ wt2,  // [128][256] bf16 (c-major)
    const float* __restrict__ b2,            // [128]
    float* __restrict__ out)                 // [M_TOT,128]
{
    __shared__ __align__(16) char smraw[64 * 256 * 2];   // 32 KB: pc ∪ hb
    __shared__ __align__(16) float Usc[64 * 36];         // 9 KB padded scaled-U
    __shared__ int idxL[64 * 3];                         // LOCAL nbr indices

    float4*         pc = reinterpret_cast<float4*>(smraw);          // [1024]
    unsigned short* hb = reinterpret_cast<unsigned short*>(smraw);  // [64*256]

    const int tid  = threadIdx.x;
    const int lane = tid & 63;
    const int wv   = tid >> 6;               // 0..7
    const int blk  = (blockIdx.x & 7) * 128 + (blockIdx.x >> 3);  // XCD swz
    const int lo   = lane & 15;
    const int hi   = lane >> 4;
    const int b    = blk >> 6;               // 64 blocks per batch

    // ---------------- Phase K: candidate cache + top-3 scan ----------------
    #pragma unroll
    for (int k = 0; k < 2; ++k) {
        const int j = tid + k * 512;
        const float* p = pos + (size_t)(b * N_PER + j) * 3;
        float a0 = p[0], a1 = p[1], a2 = p[2];
        pc[j] = make_float4(a0, a1, a2, a0*a0 + a1*a1 + a2*a2);
    }
    __syncthreads();

    {
        const int q   = tid >> 3;            // query row 0..63
        const int sub = tid & 7;
        const int m   = blk * 64 + q;
        float nqx, nqy, nqz, qq;
        {
            const float qx = pos_skip[m*3+0], qy = pos_skip[m*3+1],
                        qz = pos_skip[m*3+2];
            qq  = qx*qx + qy*qy + qz*qz;
            nqx = -2.0f*qx; nqy = -2.0f*qy; nqz = -2.0f*qz;
        }

        float d0 = 1e30f, d1 = 1e30f, d2 = 1e30f;
        int   i0 = 0,     i1 = 0,     i2 = 0;
        #pragma unroll 2
        for (int t = 0; t < 128; ++t) {
            const int j = t*8 + sub;         // wave reads 128B bcast x8
            float4 c = pc[j];
            float r = fmaf(nqx, c.x, fmaf(nqy, c.y, fmaf(nqz, c.z, qq + c.w)));
            bool c0 = r < d0, c1 = r < d1, c2 = r < d2;
            i2 = c2 ? (c1 ? i1 : j) : i2;
            i1 = c1 ? (c0 ? i0 : j) : i1;
            i0 = c0 ? j : i0;
            d2 = c2 ? (c1 ? d1 : r) : d2;
            d1 = c1 ? (c0 ? d0 : r) : d1;
            d0 = c0 ? r : d0;
        }
        // 3-level butterfly merge across the 8 sublanes, lexicographic (d, j)
        #pragma unroll
        for (int mask = 1; mask <= 4; mask <<= 1) {
            float e0 = __shfl_xor(d0, mask), e1 = __shfl_xor(d1, mask),
                  e2 = __shfl_xor(d2, mask);
            int   j0 = __shfl_xor(i0, mask), j1 = __shfl_xor(i1, mask),
                  j2 = __shfl_xor(i2, mask);
            const float ee[3] = {e0, e1, e2};
            const int   jj[3] = {j0, j1, j2};
            #pragma unroll
            for (int s = 0; s < 3; ++s) {
                const float e = ee[s]; const int j = jj[s];
                bool c0 = (e < d0) || (e == d0 && j < i0);
                bool c1 = (e < d1) || (e == d1 && j < i1);
                bool c2 = (e < d2) || (e == d2 && j < i2);
                i2 = c2 ? (c1 ? i1 : j) : i2;
                i1 = c1 ? (c0 ? i0 : j) : i1;
                i0 = c0 ? j : i0;
                d2 = c2 ? (c1 ? d1 : e) : d2;
                d1 = c1 ? (c0 ? d0 : e) : d1;
                d0 = c0 ? e : d0;
            }
        }

        // -------- fused phase U: all 8 sublanes hold the merged top-3 -------
        if (sub < 3) {
            const int jl = (sub == 0) ? i0 : (sub == 1) ? i1 : i2;
            idxL[q*3 + sub] = jl;            // local index, for phase A

            const float qx = -0.5f*nqx, qy = -0.5f*nqy, qz = -0.5f*nqz;
            float w[3];
            const int jls[3] = {i0, i1, i2};
            #pragma unroll
            for (int s = 0; s < 3; ++s) {
                float4 c = pc[jls[s]];
                float dx = c.x - qx, dy = c.y - qy, dz = c.z - qz;
                w[s] = 1.0f / fmaxf(dx*dx + dy*dy + dz*dz, 1e-16f);
            }
            const float wsub = (sub == 0) ? w[0] : (sub == 1) ? w[1] : w[2];
            const float sS   = wsub / (w[0] + w[1] + w[2]);
            const int   nb   = b * N_PER + jl;

            float RyS[9];
            #pragma unroll
            for (int t = 0; t < 9; ++t) RyS[t] = sS * lframes_skip[(size_t)m*9 + t];

            // row-interleaved: one Rx row live at a time (9+3 floats)
            float* dst = &Usc[q*36 + sub*12];
            const float* Rxp = lframes + (size_t)nb*9;
            #pragma unroll
            for (int c = 0; c < 3; ++c) {
                const float r0 = Rxp[c*3+0], r1 = Rxp[c*3+1], r2 = Rxp[c*3+2];
                #pragma unroll
                for (int a = 0; a < 3; ++a)
                    dst[a*3+c] = RyS[a*3+0]*r0 + RyS[a*3+1]*r1 + RyS[a*3+2]*r2;
            }
        }
    }

    // early x_skip staging for rows 32-63 (hb rows >=32 never alias pc)
    if (wv >= 4) {
        #pragma unroll
        for (int rr = 0; rr < 8; ++rr) {
            const int r = wv * 8 + rr;       // 32..63
            const int m = blk * 64 + r;
            hb[hsw(r, 192+lane)] = f2bf(x_skip[(size_t)m*FSKIP + lane]);
        }
    }
    __syncthreads();   // idxL + Usc visible; pc reads done before hb overwrite

    // ---------------- Phase A: build h = [y | x_skip] (bf16) ----------------
    for (int rr = 0; rr < 8; ++rr) {
        const int r = wv * 8 + rr;
        const int m = blk * 64 + r;

        float n0 = 0.f, n1 = 0.f, n2 = 0.f;
        #pragma unroll
        for (int k = 0; k < 3; ++k) {
            const int nb = b*N_PER + idxL[r*3+k];
            // 12-float aligned chunk for this neighbor (9 used, 3 pad)
            float Ub[12];
            float4* Ub4 = reinterpret_cast<float4*>(Ub);
            #pragma unroll
            for (int t = 0; t < 3; ++t)
                Ub4[t] = *reinterpret_cast<const float4*>(
                    &Usc[r*36 + k*12 + t*4]);  // bcast
            const float* xp = x + (size_t)nb*FDIM + lane*3;
            const float v0 = xp[0], v1 = xp[1], v2 = xp[2];
            n0 += Ub[0]*v0 + Ub[1]*v1 + Ub[2]*v2;
            n1 += Ub[3]*v0 + Ub[4]*v1 + Ub[5]*v2;
            n2 += Ub[6]*v0 + Ub[7]*v1 + Ub[8]*v2;
        }
        hb[hsw(r, lane*3+0)] = f2bf(n0);
        hb[hsw(r, lane*3+1)] = f2bf(n1);
        hb[hsw(r, lane*3+2)] = f2bf(n2);
        if (wv < 4)   // rows 32-63 already staged before the barrier
            hb[hsw(r, 192+lane)] = f2bf(x_skip[(size_t)m*FSKIP + lane]);
    }
    __syncthreads();

    // ---------------- GEMM1: hidden = relu(h @ W1 + b1) ----------------
    // wave wv covers cols [wv*32, wv*32+32)
    f32x4 acc[4][2];
    #pragma unroll
    for (int fi = 0; fi < 4; ++fi)
        #pragma unroll
        for (int ci = 0; ci < 2; ++ci) acc[fi][ci] = (f32x4)0.f;

    for (int ks = 0; ks < 8; ++ks) {
        const int kk = ks*32 + hi*8;
        short8v a[4], bf[2];
        #pragma unroll
        for (int fi = 0; fi < 4; ++fi) {
            const int r = fi*16 + lo;
            a[fi] = *reinterpret_cast<const short8v*>(
                &hb[r*256 + (kk ^ ((lo & 7) << 3))]);
        }
        #pragma unroll
        for (int ci = 0; ci < 2; ++ci) {
            const int cb = wv*32 + ci*16 + lo;
            bf[ci] = *reinterpret_cast<const short8v*>(&wt1[cb*256 + kk]);
        }
        #pragma unroll
        for (int fi = 0; fi < 4; ++fi)
            #pragma unroll
            for (int ci = 0; ci < 2; ++ci)
                acc[fi][ci] = __builtin_amdgcn_mfma_f32_16x16x32_bf16(
                    a[fi], bf[ci], acc[fi][ci], 0, 0, 0);
    }
    __syncthreads();   // all GEMM1 reads of h complete

    {
        float b1v[2];
        #pragma unroll
        for (int ci = 0; ci < 2; ++ci) b1v[ci] = b1[wv*32 + ci*16 + lo];
        #pragma unroll
        for (int fi = 0; fi < 4; ++fi)
            #pragma unroll
            for (int ci = 0; ci < 2; ++ci)
                #pragma unroll
                for (int q = 0; q < 4; ++q) {
                    const int r = fi*16 + hi*4 + q;
                    const int c = wv*32 + ci*16 + lo;
                    hb[hsw(r, c)] = f2bf(fmaxf(acc[fi][ci][q] + b1v[ci], 0.f));
                }
    }
    __syncthreads();

    // ---------------- GEMM2: out = hidden @ W2 + b2 ----------------
    // wave wv covers cols [wv*16, wv*16+16)
    f32x4 acc2[4];
    #pragma unroll
    for (int fi = 0; fi < 4; ++fi) acc2[fi] = (f32x4)0.f;

    for (int ks = 0; ks < 8; ++ks) {
        const int kk = ks*32 + hi*8;
        short8v a[4], bf;
        #pragma unroll
        for (int fi = 0; fi < 4; ++fi) {
            const int r = fi*16 + lo;
            a[fi] = *reinterpret_cast<const short8v*>(
                &hb[r*256 + (kk ^ ((lo & 7) << 3))]);
        }
        {
            const int cb = wv*16 + lo;
            bf = *reinterpret_cast<const short8v*>(&wt2[cb*256 + kk]);
        }
        #pragma unroll
        for (int fi = 0; fi < 4; ++fi)
            acc2[fi] = __builtin_amdgcn_mfma_f32_16x16x32_bf16(
                a[fi], bf, acc2[fi], 0, 0, 0);
    }

    {
        const float b2v = b2[wv*16 + lo];
        #pragma unroll
        for (int fi = 0; fi < 4; ++fi)
            #pragma unroll
            for (int q = 0; q < 4; ++q) {
                const int r = fi*16 + hi*4 + q;
                const int c = wv*16 + lo;
                out[(size_t)(blk*64 + r)*ODIM + c] = acc2[fi][q] + b2v;
            }
    }
}

extern "C" void kernel_launch(void* const* d_in, const int* in_sizes, int n_in,
                              void* d_out, int out_size, void* d_ws, size_t ws_size,
                              hipStream_t stream) {
    const float* x            = (const float*)d_in[0];
    const float* pos          = (const float*)d_in[1];
    const float* pos_skip     = (const float*)d_in[2];
    const float* x_skip       = (const float*)d_in[3];
    const float* lframes      = (const float*)d_in[4];
    const float* lframes_skip = (const float*)d_in[5];
    const float* W1           = (const float*)d_in[6];
    const float* b1           = (const float*)d_in[7];
    const float* W2           = (const float*)d_in[8];
    const float* b2           = (const float*)d_in[9];
    const int*   batch_skip   = (const int*)d_in[11];

    char* ws = (char*)d_ws;
    unsigned short* wt1 = (unsigned short*)ws;                 // 131072 B
    unsigned short* wt2 = (unsigned short*)(ws + 131072);      // 65536 B
    float* out  = (float*)d_out;
    float* tail = out + (size_t)M_TOT * ODIM;

    // merged prep + tail: 65536 + 32768 + 851968 = 950272 threads = 3712 blocks
    prep_tail_kernel<<<3712, 256, 0, stream>>>(W1, W2, pos_skip, batch_skip,
                                               lframes_skip, wt1, wt2, tail);

    fused_kernel<<<M_TOT/64, 512, 0, stream>>>(x, pos, pos_skip, x_skip,
                                               lframes, lframes_skip,
                                               wt1, b1, wt2, b2, out);
}